// Round 1
// baseline (261.229 us; speedup 1.0000x reference)
//
#include <hip/hip_runtime.h>

#define F 128
#define S 25

// neighbor_idx may arrive as int32 or int64 (reference uses int64; harness doc
// says integer -> const int*). Detect layout from the data: int64 little-endian
// with values in [0, 2^31) has all odd dwords == 0. P(false positive on random
// int32 in [0,1e5)) ~ 1e-20. Deterministic: same data -> same branch.
__device__ __forceinline__ bool idx_is_i64(const int* __restrict__ p) {
    return (p[1] | p[3] | p[5] | p[7]) == 0;
}

__device__ __forceinline__ int load_idx(const int* __restrict__ p, size_t i, bool is64) {
    return is64 ? p[2 * i] : p[i];
}

// ---------------------------------------------------------------------------
// K1: y = x @ W   (fp32 vector GEMM; W staged in LDS, 8 nodes per wave)
// block = 256 (4 waves). LDS: W 64KB + A-stage 16KB = 80KB -> 2 blocks/CU.
// Each wave computes an 8x128 output tile; lane covers cols {l, l+64}.
// ---------------------------------------------------------------------------
__global__ __launch_bounds__(256, 2) void gemm_xw_kernel(
    const float* __restrict__ x, const float* __restrict__ W,
    float* __restrict__ y, int N)
{
    __shared__ float Wlds[F][F];        // 64 KB, row-major: read W[k][lane] conflict-free
    __shared__ float Alds[4][8][F];     // 16 KB, per-wave staged x rows

    const int tid  = threadIdx.x;
    const int lane = tid & 63;
    const int wid  = tid >> 6;

    // cooperative W load (float4, coalesced)
    {
        const float4* Wv = (const float4*)W;
        float4* Wl = (float4*)&Wlds[0][0];
        #pragma unroll
        for (int i = 0; i < 16; ++i)
            Wl[tid + 256 * i] = Wv[tid + 256 * i];
    }
    __syncthreads();

    const int ntiles  = (N + 7) >> 3;       // 8-node tiles (12500 for N=100000)
    const int ngroups = (ntiles + 3) >> 2;  // 4 tiles per block-iteration (one per wave)

    for (int g = blockIdx.x; g < ngroups; g += gridDim.x) {
        const int tile = g * 4 + wid;
        const int n0   = tile * 8;
        const bool tile_ok = (tile < ntiles);

        // stage this wave's 8 x-rows into LDS (float4 coalesced)
        #pragma unroll
        for (int i = 0; i < 4; ++i) {
            int e = i * 64 + lane;          // 0..255 -> 256 float4 = 8x128 floats
            int row = e >> 5, c4 = e & 31;
            int n = n0 + row;
            float4 v = (tile_ok && n < N) ? ((const float4*)(x + (size_t)n * F))[c4]
                                          : make_float4(0.f, 0.f, 0.f, 0.f);
            ((float4*)&Alds[wid][row][0])[c4] = v;
        }
        __syncthreads();

        float acc0[8] = {0.f, 0.f, 0.f, 0.f, 0.f, 0.f, 0.f, 0.f};
        float acc1[8] = {0.f, 0.f, 0.f, 0.f, 0.f, 0.f, 0.f, 0.f};

        for (int kt = 0; kt < F / 4; ++kt) {
            float4 a[8];
            #pragma unroll
            for (int j = 0; j < 8; ++j)     // b128 LDS broadcasts (same addr across wave)
                a[j] = ((const float4*)&Alds[wid][j][0])[kt];
            #pragma unroll
            for (int dk = 0; dk < 4; ++dk) {
                float w0 = Wlds[kt * 4 + dk][lane];
                float w1 = Wlds[kt * 4 + dk][lane + 64];
                #pragma unroll
                for (int j = 0; j < 8; ++j) {
                    float av = (&a[j].x)[dk];   // dk is a compile-time literal (unrolled)
                    acc0[j] += av * w0;
                    acc1[j] += av * w1;
                }
            }
        }

        if (tile_ok) {
            #pragma unroll
            for (int j = 0; j < 8; ++j) {
                int n = n0 + j;
                if (n < N) {
                    y[(size_t)n * F + lane]      = acc0[j];
                    y[(size_t)n * F + lane + 64] = acc1[j];
                }
            }
        }
        __syncthreads();    // protect Alds before next iteration overwrites it
    }
}

// ---------------------------------------------------------------------------
// K2: out[n] = (y[n] + sum_s y[idx[n,s]]) / 26 + b
// One wave per node, lane covers cols {2l, 2l+1} as float2.
// 26 independent row-gathers per node -> deep ILP to hide L2/L3 latency.
// ---------------------------------------------------------------------------
__global__ __launch_bounds__(256) void gather_agg_kernel(
    const float* __restrict__ y, const int* __restrict__ nbr,
    const float* __restrict__ bias, float* __restrict__ out, int N)
{
    const int lane = threadIdx.x & 63;
    const int w0   = blockIdx.x * 4 + (threadIdx.x >> 6);
    const int nw   = gridDim.x * 4;
    const bool is64 = idx_is_i64(nbr);
    const float2 bb = ((const float2*)bias)[lane];
    const float inv = 1.0f / (float)(S + 1);

    for (int n = w0; n < N; n += nw) {
        int ids[S];
        #pragma unroll
        for (int s = 0; s < S; ++s)
            ids[s] = load_idx(nbr, (size_t)n * S + s, is64);

        float2 acc = ((const float2*)(y + (size_t)n * F))[lane];
        #pragma unroll
        for (int s = 0; s < S; ++s) {
            float2 v = ((const float2*)(y + (size_t)ids[s] * F))[lane];
            acc.x += v.x; acc.y += v.y;
        }
        float2 o;
        o.x = acc.x * inv + bb.x;
        o.y = acc.y * inv + bb.y;
        ((float2*)(out + (size_t)n * F))[lane] = o;
    }
}

// ---------------------------------------------------------------------------
// Fallback if d_ws is too small for y: fused gather+GEMM (slow but correct).
// ---------------------------------------------------------------------------
__global__ __launch_bounds__(256) void fused_fallback_kernel(
    const float* __restrict__ x, const int* __restrict__ nbr,
    const float* __restrict__ W, const float* __restrict__ bias,
    float* __restrict__ out, int N)
{
    __shared__ float aggs[4][F];
    const int lane = threadIdx.x & 63;
    const int wid  = threadIdx.x >> 6;
    const bool is64 = idx_is_i64(nbr);
    const float inv = 1.0f / (float)(S + 1);
    const int stride = gridDim.x * 4;

    for (int base = blockIdx.x * 4; base < N; base += stride) {  // block-uniform trip count
        int n = base + wid;
        bool act = n < N;
        float2 acc = make_float2(0.f, 0.f);
        if (act) {
            acc = ((const float2*)(x + (size_t)n * F))[lane];
            for (int s = 0; s < S; ++s) {
                int id = load_idx(nbr, (size_t)n * S + s, is64);
                float2 v = ((const float2*)(x + (size_t)id * F))[lane];
                acc.x += v.x; acc.y += v.y;
            }
        }
        aggs[wid][2 * lane]     = acc.x * inv;
        aggs[wid][2 * lane + 1] = acc.y * inv;
        __syncthreads();
        if (act) {
            float o0 = bias[lane], o1 = bias[lane + 64];
            for (int k = 0; k < F; ++k) {
                float a = aggs[wid][k];
                o0 += a * W[k * F + lane];
                o1 += a * W[k * F + lane + 64];
            }
            out[(size_t)n * F + lane]      = o0;
            out[(size_t)n * F + lane + 64] = o1;
        }
        __syncthreads();
    }
}

extern "C" void kernel_launch(void* const* d_in, const int* in_sizes, int n_in,
                              void* d_out, int out_size, void* d_ws, size_t ws_size,
                              hipStream_t stream) {
    const float* x    = (const float*)d_in[0];
    const int*   nbr  = (const int*)d_in[1];
    const float* W    = (const float*)d_in[2];
    const float* bias = (const float*)d_in[3];
    float* out = (float*)d_out;
    const int N = in_sizes[0] / F;                    // 100000
    const size_t need = (size_t)N * F * sizeof(float); // 51.2 MB for y

    if (ws_size >= need) {
        float* y = (float*)d_ws;
        gemm_xw_kernel<<<512, 256, 0, stream>>>(x, W, y, N);
        gather_agg_kernel<<<2048, 256, 0, stream>>>(y, nbr, bias, out, N);
    } else {
        fused_fallback_kernel<<<2048, 256, 0, stream>>>(x, nbr, W, bias, out, N);
    }
}

// Round 2
// 127.679 us; speedup vs baseline: 2.0460x; 2.0460x over previous
//
#include <hip/hip_runtime.h>

#define F 128
#define S 25

typedef __attribute__((ext_vector_type(8))) short bf16x8;
typedef __attribute__((ext_vector_type(4))) float f32x4;

// round-to-nearest-even f32 -> bf16 bits
__device__ __forceinline__ ushort f2bf(float f) {
    uint u = __float_as_uint(f);
    return (ushort)((u + 0x7FFFu + ((u >> 16) & 1u)) >> 16);
}
__device__ __forceinline__ float bf_lo(uint v) { return __uint_as_float(v << 16); }
__device__ __forceinline__ float bf_hi(uint v) { return __uint_as_float(v & 0xFFFF0000u); }

// neighbor_idx may arrive as int32 or int64 (reference uses int64). Detect from
// data: int64 LE with values < 2^31 has all odd dwords zero. Deterministic.
__device__ __forceinline__ bool idx_is_i64(const int* __restrict__ p) {
    return (p[1] | p[3] | p[5] | p[7]) == 0;
}
__device__ __forceinline__ int load_idx(const int* __restrict__ p, size_t i, bool is64) {
    return is64 ? p[2 * i] : p[i];
}

// ---------------------------------------------------------------------------
// K1: y_bf16 = bf16(x) @ bf16(W) via v_mfma_f32_16x16x32_bf16, fp32 accum.
// Block 256 = 4 waves; each wave computes a 16x128 output tile (8 n-tiles,
// K-loop of 4). W staged once per block into LDS in exact B-fragment order:
// WF[kt][nt][lane][b] = W[kt*32 + 8*(lane>>4) + b][nt*16 + (lane&15)]
// so the read is a linear 16B/lane ds_read_b128 (conflict-free).
// Verified layouts (learn_hip m89/m91):
//   A: row = lane&15, k = 8*(lane>>4)+b      (8 consecutive k per lane)
//   D: col = lane&15, row = 4*(lane>>4)+reg
// ---------------------------------------------------------------------------
__global__ __launch_bounds__(256) void gemm_xw_bf16(
    const float* __restrict__ x, const float* __restrict__ W,
    ushort* __restrict__ y, int N)
{
    __shared__ ushort WF[4][8][64][8];   // 32 KB

    const int tid  = threadIdx.x;
    const int lane = tid & 63;
    const int wid  = tid >> 6;

    // Fill WF (coalesced-enough: 16 consecutive n per 16 lanes; W is 64 KB, L2-hot)
    for (int e = tid; e < 4 * 8 * 64; e += 256) {
        const int l  = e & 63;
        const int nt = (e >> 6) & 7;
        const int kt = e >> 9;
        const int k0 = kt * 32 + (l >> 4) * 8;
        const int n  = nt * 16 + (l & 15);
        #pragma unroll
        for (int b = 0; b < 8; ++b)
            WF[kt][nt][l][b] = f2bf(W[(size_t)(k0 + b) * F + n]);
    }
    __syncthreads();

    const int n0 = blockIdx.x * 64 + wid * 16;      // this wave's 16-row tile
    const int arow = n0 + (lane & 15);
    const int arow_c = arow < N ? arow : N - 1;      // clamp; garbage only feeds masked rows
    const float* xrow = x + (size_t)arow_c * F + (lane >> 4) * 8;

    f32x4 acc[8];
    #pragma unroll
    for (int nt = 0; nt < 8; ++nt) acc[nt] = (f32x4){0.f, 0.f, 0.f, 0.f};

    #pragma unroll
    for (int kt = 0; kt < 4; ++kt) {
        float4 a0 = *(const float4*)(xrow + kt * 32);
        float4 a1 = *(const float4*)(xrow + kt * 32 + 4);
        bf16x8 af;
        af[0] = (short)f2bf(a0.x); af[1] = (short)f2bf(a0.y);
        af[2] = (short)f2bf(a0.z); af[3] = (short)f2bf(a0.w);
        af[4] = (short)f2bf(a1.x); af[5] = (short)f2bf(a1.y);
        af[6] = (short)f2bf(a1.z); af[7] = (short)f2bf(a1.w);
        #pragma unroll
        for (int nt = 0; nt < 8; ++nt) {
            bf16x8 bf = *(const bf16x8*)&WF[kt][nt][lane][0];
            acc[nt] = __builtin_amdgcn_mfma_f32_16x16x32_bf16(af, bf, acc[nt], 0, 0, 0);
        }
    }

    const int drow0 = n0 + (lane >> 4) * 4;
    const int dcol  = lane & 15;
    #pragma unroll
    for (int nt = 0; nt < 8; ++nt) {
        #pragma unroll
        for (int r = 0; r < 4; ++r) {
            const int row = drow0 + r;
            if (row < N)
                y[(size_t)row * F + nt * 16 + dcol] = f2bf(acc[nt][r]);
        }
    }
}

// ---------------------------------------------------------------------------
// K2: out[n] = (y[n] + sum_s y[idx[n,s]]) / 26 + b   (y in bf16, out fp32)
// One wave per node; lane covers cols {2l, 2l+1} via one dword (2 bf16).
// Node index made wave-uniform via readfirstlane so idx loads go scalar.
// 26 independent 256 B row reads in flight per node.
// ---------------------------------------------------------------------------
__global__ __launch_bounds__(256) void gather_agg_bf16(
    const ushort* __restrict__ y, const int* __restrict__ nbr,
    const float* __restrict__ bias, float* __restrict__ out, int N)
{
    const int lane = threadIdx.x & 63;
    const int wid  = threadIdx.x >> 6;
    const bool is64 = idx_is_i64(nbr);
    const float2 bb = ((const float2*)bias)[lane];
    const float inv = 1.0f / (float)(S + 1);
    const int nw = gridDim.x * 4;
    const uint* yw = (const uint*)y;     // 64 dwords per row

    for (int n = blockIdx.x * 4 + wid; n < N; n += nw) {
        const int nu = __builtin_amdgcn_readfirstlane(n);

        int ids[S];
        #pragma unroll
        for (int s = 0; s < S; ++s)
            ids[s] = load_idx(nbr, (size_t)nu * S + s, is64);

        uint vs[S];
        #pragma unroll
        for (int s = 0; s < S; ++s)
            vs[s] = yw[(size_t)ids[s] * 64 + lane];
        const uint v0 = yw[(size_t)nu * 64 + lane];

        float ax = bf_lo(v0), ay = bf_hi(v0);
        #pragma unroll
        for (int s = 0; s < S; ++s) {
            ax += bf_lo(vs[s]);
            ay += bf_hi(vs[s]);
        }
        float2 o;
        o.x = ax * inv + bb.x;
        o.y = ay * inv + bb.y;
        ((float2*)(out + (size_t)nu * F))[lane] = o;
    }
}

// ---------------------------------------------------------------------------
// Fallback if d_ws too small: fused fp32 gather+GEMM (slow but correct).
// ---------------------------------------------------------------------------
__global__ __launch_bounds__(256) void fused_fallback_kernel(
    const float* __restrict__ x, const int* __restrict__ nbr,
    const float* __restrict__ W, const float* __restrict__ bias,
    float* __restrict__ out, int N)
{
    __shared__ float aggs[4][F];
    const int lane = threadIdx.x & 63;
    const int wid  = threadIdx.x >> 6;
    const bool is64 = idx_is_i64(nbr);
    const float inv = 1.0f / (float)(S + 1);
    const int stride = gridDim.x * 4;

    for (int base = blockIdx.x * 4; base < N; base += stride) {
        int n = base + wid;
        bool act = n < N;
        float2 acc = make_float2(0.f, 0.f);
        if (act) {
            acc = ((const float2*)(x + (size_t)n * F))[lane];
            for (int s = 0; s < S; ++s) {
                int id = load_idx(nbr, (size_t)n * S + s, is64);
                float2 v = ((const float2*)(x + (size_t)id * F))[lane];
                acc.x += v.x; acc.y += v.y;
            }
        }
        aggs[wid][2 * lane]     = acc.x * inv;
        aggs[wid][2 * lane + 1] = acc.y * inv;
        __syncthreads();
        if (act) {
            float o0 = bias[lane], o1 = bias[lane + 64];
            for (int k = 0; k < F; ++k) {
                float a = aggs[wid][k];
                o0 += a * W[k * F + lane];
                o1 += a * W[k * F + lane + 64];
            }
            out[(size_t)n * F + lane]      = o0;
            out[(size_t)n * F + lane + 64] = o1;
        }
        __syncthreads();
    }
}

extern "C" void kernel_launch(void* const* d_in, const int* in_sizes, int n_in,
                              void* d_out, int out_size, void* d_ws, size_t ws_size,
                              hipStream_t stream) {
    const float* x    = (const float*)d_in[0];
    const int*   nbr  = (const int*)d_in[1];
    const float* W    = (const float*)d_in[2];
    const float* bias = (const float*)d_in[3];
    float* out = (float*)d_out;
    const int N = in_sizes[0] / F;                        // 100000
    const size_t need = (size_t)N * F * sizeof(ushort);   // 25.6 MB bf16 y

    if (ws_size >= need) {
        ushort* y = (ushort*)d_ws;
        const int tiles = (N + 63) / 64;                  // 1563
        gemm_xw_bf16<<<tiles, 256, 0, stream>>>(x, W, y, N);
        gather_agg_bf16<<<2048, 256, 0, stream>>>(y, nbr, bias, out, N);
    } else {
        fused_fallback_kernel<<<2048, 256, 0, stream>>>(x, nbr, W, bias, out, N);
    }
}